// Round 16
// baseline (5899.141 us; speedup 1.0000x reference)
//
#include <hip/hip_runtime.h>

// CustomLSTM — Round 16: r15 minus barrier-2 and cross-wave publish coupling.
//   (1) PER-WAVE publish flags: each publishing wave (0-3) drains its own sc1
//       stores with a wave-level s_waitcnt vmcnt(0) and sets flags4[wg*4+pw]
//       (relaxed sc1). No block barrier, no release-store L2 writeback.
//   (2) gbuf parity double-buffer (2 x 64KB) legalizes barrier-2 removal:
//       step t reads gbuf[t&1], step t+1 writes gbuf[~t&1] — the race the
//       barrier guarded is gone by construction.
//   (3) U-hi frags move LDS -> registers (+32 VGPR; 1 WG/CU so free), making
//       room for (2) and deleting the preamble staging barrier.
//   Consumers poll 32 flags (8 producer WGs x 4 pub-waves) with lanes<32.
// Barriers/step: ONE (gbuf -> cell).
//
// ws layout (121 MB):
//   0         flags4  1024 (64wg x 4 pub-waves)
//   1048576   vfragH  8388608   | 9437184  vfragL 8388608
//   17825792  ufragH  4194304   | 22020096 ufragL 4194304
//   26214400  xfragH 16777216   | 42991616 xfragL 16777216
//   59768832  hSeqH  33554432   | 93323264 hSeqL 33554432   (end 126877696)

typedef __bf16 bf16x8 __attribute__((ext_vector_type(8)));
typedef float f32x16 __attribute__((ext_vector_type(16)));

#define NWG 64
#define T_STEPS 512
#define HID 1024
#define BS 32
#define WS_FULL 126877696

__device__ __forceinline__ unsigned short f2bf(float f) {
  unsigned int u = __float_as_uint(f);
  u = (u + 0x7FFFu + ((u >> 16) & 1u)) >> 16;
  return (unsigned short)u;
}
__device__ __forceinline__ float b2f(unsigned short s) {
  return __uint_as_float(((unsigned int)s) << 16);
}
__device__ __forceinline__ float sigm(float v) {
  v = fminf(fmaxf(v, -30.f), 30.f);
  return 1.f / (1.f + __expf(-v));
}
__device__ __forceinline__ float tanh_(float v) {
  v = fminf(fmaxf(v, -15.f), 15.f);
  float e = __expf(-2.f * v);
  return (1.f - e) / (1.f + e);
}

// ---- x -> bf16 A-frags hi+lo: [t][kt 0..31][lane][4 dwords] ----
__global__ void cvt_x_kernel(const float* __restrict__ x,
                             unsigned int* __restrict__ xfH,
                             unsigned int* __restrict__ xfL) {
  const int t = blockIdx.x;
  const int tid = threadIdx.x;
  __shared__ float xs[32 * 512];
  {
    const int b = tid >> 3;
    const int k0 = (tid & 7) * 64;
    const float* src = x + ((size_t)(b * 512 + t)) * 512 + k0;
    for (int i = 0; i < 64; i += 4) {
      float4 v = *reinterpret_cast<const float4*>(src + i);
      xs[b * 512 + k0 + i + 0] = v.x;
      xs[b * 512 + k0 + i + 1] = v.y;
      xs[b * 512 + k0 + i + 2] = v.z;
      xs[b * 512 + k0 + i + 3] = v.w;
    }
  }
  __syncthreads();
  unsigned int* dH = xfH + (size_t)t * 8192;
  unsigned int* dL = xfL + (size_t)t * 8192;
  for (int i = 0; i < 32; ++i) {
    int idx = i * 256 + tid;
    int kt = idx >> 8;
    int pos = idx & 255;
    int lane = pos >> 2;
    int r = pos & 3;
    int kk = 8 * (lane >> 5) + 2 * r;
    int b2 = lane & 31;
    float f0 = xs[b2 * 512 + kt * 16 + kk];
    float f1 = xs[b2 * 512 + kt * 16 + kk + 1];
    unsigned short h0 = f2bf(f0), h1 = f2bf(f1);
    unsigned short l0 = f2bf(f0 - b2f(h0)), l1 = f2bf(f1 - b2f(h1));
    dH[idx] = (unsigned int)h0 | ((unsigned int)h1 << 16);
    dL[idx] = (unsigned int)l0 | ((unsigned int)l1 << 16);
  }
}

// ---- U,V -> B-frags hi+lo. V: kt 0..63. U: kt 64..95 ----
__global__ void cvt_uv_kernel(const float* Uf, const float* Vf,
                              const float* Ui, const float* Vi,
                              const float* Uo, const float* Vo,
                              const float* Ug, const float* Vg,
                              unsigned int* __restrict__ vfH,
                              unsigned int* __restrict__ vfL,
                              unsigned int* __restrict__ ufH,
                              unsigned int* __restrict__ ufL) {
  int blk = blockIdx.x;  // 64*2*96
  int kt = blk % 96;
  int nt = (blk / 96) & 1;
  int wg = blk / 192;
  int lane = threadIdx.x;
  int col32 = lane & 31;
  int c64 = nt * 32 + col32;
  int gate = c64 >> 4;
  int jg = wg * 16 + (c64 & 15);
  const float* V_ = (gate == 0) ? Vf : (gate == 1) ? Vi : (gate == 2) ? Vo : Vg;
  const float* U_ = (gate == 0) ? Uf : (gate == 1) ? Ui : (gate == 2) ? Uo : Ug;
  for (int r = 0; r < 4; ++r) {
    int kk = 8 * (lane >> 5) + 2 * r;
    if (kt < 64) {
      int K = kt * 16 + kk;
      float f0 = V_[(size_t)K * HID + jg];
      float f1 = V_[(size_t)(K + 1) * HID + jg];
      unsigned short h0 = f2bf(f0), h1 = f2bf(f1);
      unsigned short l0 = f2bf(f0 - b2f(h0)), l1 = f2bf(f1 - b2f(h1));
      size_t idx = ((size_t)(wg * 2 + nt) * 64 + kt) * 256 + lane * 4 + r;
      vfH[idx] = (unsigned int)h0 | ((unsigned int)h1 << 16);
      vfL[idx] = (unsigned int)l0 | ((unsigned int)l1 << 16);
    } else {
      int K = (kt - 64) * 16 + kk;
      float f0 = U_[(size_t)K * HID + jg];
      float f1 = U_[(size_t)(K + 1) * HID + jg];
      unsigned short h0 = f2bf(f0), h1 = f2bf(f1);
      unsigned short l0 = f2bf(f0 - b2f(h0)), l1 = f2bf(f1 - b2f(h1));
      size_t idx = ((size_t)(wg * 2 + nt) * 32 + (kt - 64)) * 256 + lane * 4 + r;
      ufH[idx] = (unsigned int)h0 | ((unsigned int)h1 << 16);
      ufL[idx] = (unsigned int)l0 | ((unsigned int)l1 << 16);
    }
  }
}

__device__ __forceinline__ int gidx(int nt, int w, int row, int col) {
  return ((nt * 8 + w) * 32 + row) * 32 + (col ^ row);
}

// ---- persistent recurrent kernel: 64 WGs x 512 threads (8 waves) ----
__global__ __launch_bounds__(512, 1) void lstm_main(
    const unsigned short* __restrict__ ufragH,
    const unsigned short* __restrict__ ufragL,
    const unsigned short* __restrict__ vfragH,
    const unsigned short* __restrict__ vfragL,
    const unsigned short* __restrict__ xfragH,
    const unsigned short* __restrict__ xfragL,
    unsigned int* hfH, unsigned int* hfL, unsigned int* flags4,
    const float* __restrict__ bfv, const float* __restrict__ biv,
    const float* __restrict__ bov, const float* __restrict__ bgv) {
  __shared__ float gbuf[2 * 16384];  // 128 KB: parity double-buffered

  const int wg = blockIdx.x;
  const int tid = threadIdx.x;
  const int lane = tid & 63;
  const int w = tid >> 6;

  __builtin_amdgcn_fence(__ATOMIC_ACQUIRE, "agent");  // replay-stale L2 kill

  // loop-invariant frags in registers: U hi+lo (4 kt each nt), V hi+lo
  bf16x8 uH[2][4], uL[2][4], vH[2][8], vL[2][8];
#pragma unroll
  for (int nt = 0; nt < 2; ++nt) {
    const bf16x8* bh = reinterpret_cast<const bf16x8*>(ufragH + (size_t)wg * 32768);
    const bf16x8* bl = reinterpret_cast<const bf16x8*>(ufragL + (size_t)wg * 32768);
#pragma unroll
    for (int p = 0; p < 4; ++p) {
      uH[nt][p] = bh[(nt * 32 + w * 4 + p) * 64 + lane];
      uL[nt][p] = bl[(nt * 32 + w * 4 + p) * 64 + lane];
    }
    const bf16x8* vh =
        reinterpret_cast<const bf16x8*>(vfragH + (size_t)((wg * 2 + nt) * 64) * 512);
    const bf16x8* vl =
        reinterpret_cast<const bf16x8*>(vfragL + (size_t)((wg * 2 + nt) * 64) * 512);
#pragma unroll
    for (int q = 0; q < 8; ++q) {
      vH[nt][q] = vh[(w * 8 + q) * 64 + lane];
      vL[nt][q] = vl[(w * 8 + q) * 64 + lane];
    }
  }

  // cell ownership (r13 mapping — conflict-free gbuf reads)
  const int b_ = tid & 31;
  const int jp_ = (tid >> 5) & 7;
  const int jg0 = wg * 16 + 2 * jp_;
  const float Bf0 = bfv[jg0], Bf1 = bfv[jg0 + 1];
  const float Bi0 = biv[jg0], Bi1 = biv[jg0 + 1];
  const float Bo0 = bov[jg0], Bo1 = bov[jg0 + 1];
  const float Bg0 = bgv[jg0], Bg1 = bgv[jg0 + 1];
  float c0 = 0.f, c1 = 0.f;
  const int hw = wg * 256 + (b_ + 32 * (jp_ >> 2)) * 4 + (jp_ & 3);

#pragma unroll 1
  for (int t = 0; t < T_STEPS; ++t) {
    f32x16 acc0 = {};
    f32x16 acc1 = {};

    // ---- x@U hi+lo (no h dependency) ----
    {
      const bf16x8* axh = reinterpret_cast<const bf16x8*>(xfragH + (size_t)t * 16384);
      const bf16x8* axl = reinterpret_cast<const bf16x8*>(xfragL + (size_t)t * 16384);
#pragma unroll
      for (int p = 0; p < 4; ++p) {
        int ktx = w * 4 + p;
        bf16x8 ah = axh[ktx * 64 + lane];
        bf16x8 al = axl[ktx * 64 + lane];
        acc0 = __builtin_amdgcn_mfma_f32_32x32x16_bf16(ah, uH[0][p], acc0, 0, 0, 0);
        acc0 = __builtin_amdgcn_mfma_f32_32x32x16_bf16(ah, uL[0][p], acc0, 0, 0, 0);
        acc0 = __builtin_amdgcn_mfma_f32_32x32x16_bf16(al, uH[0][p], acc0, 0, 0, 0);
        acc1 = __builtin_amdgcn_mfma_f32_32x32x16_bf16(ah, uH[1][p], acc1, 0, 0, 0);
        acc1 = __builtin_amdgcn_mfma_f32_32x32x16_bf16(ah, uL[1][p], acc1, 0, 0, 0);
        acc1 = __builtin_amdgcn_mfma_f32_32x32x16_bf16(al, uH[1][p], acc1, 0, 0, 0);
      }
    }

    // ---- per-wave wait: 8 producer WGs x 4 pub-waves, then h@V ----
    if (t > 0) {
      if (lane < 32) {
        const int pidx = (w * 8 + (lane >> 2)) * 4 + (lane & 3);
        while (__hip_atomic_load(&flags4[pidx], __ATOMIC_RELAXED,
                                 __HIP_MEMORY_SCOPE_AGENT) < (unsigned int)t) {
        }
      }
      const bf16x8* ahh = reinterpret_cast<const bf16x8*>(
          reinterpret_cast<const unsigned short*>(hfH) + (size_t)(t - 1) * 32768);
      const bf16x8* ahl = reinterpret_cast<const bf16x8*>(
          reinterpret_cast<const unsigned short*>(hfL) + (size_t)(t - 1) * 32768);
      bf16x8 aH[8], aL[8];
#pragma unroll
      for (int q = 0; q < 8; ++q) {
        aH[q] = ahh[(w * 8 + q) * 64 + lane];
        aL[q] = ahl[(w * 8 + q) * 64 + lane];
      }
#pragma unroll
      for (int q = 0; q < 8; ++q) {
        acc0 = __builtin_amdgcn_mfma_f32_32x32x16_bf16(aH[q], vH[0][q], acc0, 0, 0, 0);
        acc0 = __builtin_amdgcn_mfma_f32_32x32x16_bf16(aH[q], vL[0][q], acc0, 0, 0, 0);
        acc0 = __builtin_amdgcn_mfma_f32_32x32x16_bf16(aL[q], vH[0][q], acc0, 0, 0, 0);
        acc1 = __builtin_amdgcn_mfma_f32_32x32x16_bf16(aH[q], vH[1][q], acc1, 0, 0, 0);
        acc1 = __builtin_amdgcn_mfma_f32_32x32x16_bf16(aH[q], vL[1][q], acc1, 0, 0, 0);
        acc1 = __builtin_amdgcn_mfma_f32_32x32x16_bf16(aL[q], vH[1][q], acc1, 0, 0, 0);
      }
    }

    // ---- write partial C tiles into parity half (XOR-swizzled) ----
    {
      const int par = (t & 1) * 16384;
      const int colw = lane & 31;
      const int rbase = 4 * (lane >> 5);
#pragma unroll
      for (int r = 0; r < 16; ++r) {
        int row = (r & 3) + 8 * (r >> 2) + rbase;
        gbuf[par + gidx(0, w, row, colw)] = acc0[r];
        gbuf[par + gidx(1, w, row, colw)] = acc1[r];
      }
    }
    __syncthreads();  // the ONE barrier: gbuf(par) complete before cell reads

    // ---- cell update (waves 0-3) + publish + per-wave flag ----
    if (tid < 256) {
      const int par = (t & 1) * 16384;
      const int jl0 = 2 * jp_, jl1 = jl0 + 1;
      float gf0 = Bf0, gf1 = Bf1, gi0 = Bi0, gi1 = Bi1;
      float go0 = Bo0, go1 = Bo1, gg0 = Bg0, gg1 = Bg1;
#pragma unroll
      for (int ww = 0; ww < 8; ++ww) {
        gf0 += gbuf[par + gidx(0, ww, b_, jl0)];
        gf1 += gbuf[par + gidx(0, ww, b_, jl1)];
        gi0 += gbuf[par + gidx(0, ww, b_, 16 + jl0)];
        gi1 += gbuf[par + gidx(0, ww, b_, 16 + jl1)];
        go0 += gbuf[par + gidx(1, ww, b_, jl0)];
        go1 += gbuf[par + gidx(1, ww, b_, jl1)];
        gg0 += gbuf[par + gidx(1, ww, b_, 16 + jl0)];
        gg1 += gbuf[par + gidx(1, ww, b_, 16 + jl1)];
      }
      c0 = sigm(gf0) * c0 + sigm(gi0) * tanh_(gg0);
      c1 = sigm(gf1) * c1 + sigm(gi1) * tanh_(gg1);
      float h0 = sigm(go0) * tanh_(c0);
      float h1 = sigm(go1) * tanh_(c1);
      unsigned short h0h = f2bf(h0), h1h = f2bf(h1);
      unsigned short h0l = f2bf(h0 - b2f(h0h)), h1l = f2bf(h1 - b2f(h1h));
      unsigned int hvH = (unsigned int)h0h | ((unsigned int)h1h << 16);
      unsigned int hvL = (unsigned int)h0l | ((unsigned int)h1l << 16);
      size_t base = (size_t)t * 16384 + hw;
      __hip_atomic_store(&hfH[base], hvH, __ATOMIC_RELAXED,
                         __HIP_MEMORY_SCOPE_AGENT);
      __hip_atomic_store(&hfL[base], hvL, __ATOMIC_RELAXED,
                         __HIP_MEMORY_SCOPE_AGENT);
      // wave-level drain of THIS wave's sc1 publishes, then per-wave flag
      asm volatile("s_waitcnt vmcnt(0)" ::: "memory");
      if ((tid & 63) == 0) {
        __hip_atomic_store(&flags4[wg * 4 + (tid >> 6)], (unsigned int)(t + 1),
                           __ATOMIC_RELAXED, __HIP_MEMORY_SCOPE_AGENT);
      }
    }
    // no second barrier: gbuf parity protects t+1 writes vs t reads
  }
}

// ---- epilogue: expand h planes (hi+lo bf16) -> f32 out ----
__global__ __launch_bounds__(256) void expand_out(
    const unsigned int* __restrict__ hfH, const unsigned int* __restrict__ hfL,
    float* __restrict__ out) {
  __builtin_amdgcn_fence(__ATOMIC_ACQUIRE, "agent");  // replay-stale L2 kill
  const int tid = threadIdx.x;
#pragma unroll
  for (int i = 0; i < 4; ++i) {
    size_t g = (size_t)blockIdx.x * 1024 + i * 256 + tid;
    int t = (int)(g >> 14);
    int d = (int)(g & 16383);
    int wg = d >> 8;
    int off = d & 255;
    int lane_h = off >> 2;
    int r_h = off & 3;
    int b = lane_h & 31;
    int jp = (lane_h >> 5) * 4 + r_h;
    int j0 = wg * 16 + 2 * jp;
    unsigned int uH = hfH[g];
    unsigned int uL = hfL[g];
    float f0 = b2f((unsigned short)(uH & 0xFFFF)) + b2f((unsigned short)(uL & 0xFFFF));
    float f1 = b2f((unsigned short)(uH >> 16)) + b2f((unsigned short)(uL >> 16));
    float2 v = make_float2(f0, f1);
    *reinterpret_cast<float2*>(out + 32768 + ((size_t)(b * T_STEPS + t)) * HID + j0) = v;
    if (t == T_STEPS - 1) {
      *reinterpret_cast<float2*>(out + (size_t)b * HID + j0) = v;
    }
  }
}

// ================= r9 fallback (proven) =================
__global__ __launch_bounds__(256) void r9_step_gemm(
    const float* __restrict__ x, const float* __restrict__ hbuf,
    const float* __restrict__ Vf, const float* __restrict__ Vi,
    const float* __restrict__ Vo, const float* __restrict__ Vg,
    const float* __restrict__ Uf, const float* __restrict__ Ui,
    const float* __restrict__ Uo, const float* __restrict__ Ug,
    float* __restrict__ P, int t) {
  const int kb = blockIdx.x;
  const int cb = blockIdx.y;
  const int tidx = threadIdx.x;
  const int gate = cb >> 2;
  const int j = (cb & 3) * 256 + tidx;
  const int col = cb * 256 + tidx;
  const float* V_ = (gate == 0) ? Vf : (gate == 1) ? Vi : (gate == 2) ? Vo : Vg;
  const float* U_ = (gate == 0) ? Uf : (gate == 1) ? Ui : (gate == 2) ? Uo : Ug;
  __shared__ float hs[BS][32];
  __shared__ float xs2[BS][32];
  {
    int idx = tidx * 4;
#pragma unroll
    for (int i = 0; i < 4; ++i, ++idx) {
      int b = idx >> 5, u = idx & 31;
      hs[b][u] = hbuf[b * HID + kb * 32 + u];
      if (kb < 16) xs2[b][u] = x[((size_t)b * T_STEPS + t) * 512 + kb * 32 + u];
    }
  }
  __syncthreads();
  float acc[BS];
#pragma unroll
  for (int b = 0; b < BS; ++b) acc[b] = 0.f;
  const float* vp = V_ + (size_t)(kb * 32) * HID + j;
#pragma unroll 4
  for (int k = 0; k < 32; ++k) {
    float vv = vp[(size_t)k * HID];
#pragma unroll
    for (int b = 0; b < BS; ++b) acc[b] += hs[b][k] * vv;
  }
  if (kb < 16) {
    const float* up = U_ + (size_t)(kb * 32) * HID + j;
#pragma unroll 4
    for (int k = 0; k < 32; ++k) {
      float uv = up[(size_t)k * HID];
#pragma unroll
      for (int b = 0; b < BS; ++b) acc[b] += xs2[b][k] * uv;
    }
  }
  float* pp = P + (size_t)kb * BS * 4096 + col;
#pragma unroll
  for (int b = 0; b < BS; ++b) pp[(size_t)b * 4096] = acc[b];
}

__global__ __launch_bounds__(256) void r9_step_cell(
    const float* __restrict__ P,
    const float* __restrict__ bfv, const float* __restrict__ biv,
    const float* __restrict__ bov, const float* __restrict__ bgv,
    float* __restrict__ hbuf, float* __restrict__ cbuf,
    float* __restrict__ out, int t) {
  const int idx = blockIdx.x * 256 + threadIdx.x;
  const int b = idx >> 10, j = idx & 1023;
  float gf = bfv[j], gi = biv[j], go = bov[j], gg = bgv[j];
  const float* pb = P + (size_t)b * 4096;
#pragma unroll 8
  for (int kb = 0; kb < 32; ++kb) {
    const float* pk = pb + (size_t)kb * BS * 4096;
    gf += pk[j];
    gi += pk[1024 + j];
    go += pk[2048 + j];
    gg += pk[3072 + j];
  }
  float fs = sigm(gf), is = sigm(gi), os = sigm(go), gt = tanh_(gg);
  float c = fs * cbuf[idx] + is * gt;
  cbuf[idx] = c;
  float h = os * tanh_(c);
  hbuf[idx] = h;
  out[32768 + ((size_t)b * T_STEPS + t) * HID + j] = h;
  if (t == T_STEPS - 1) out[(size_t)b * HID + j] = h;
}

extern "C" void kernel_launch(void* const* d_in, const int* in_sizes, int n_in,
                              void* d_out, int out_size, void* d_ws, size_t ws_size,
                              hipStream_t stream) {
  const float *x, *Uf, *Vf, *bf, *Ui, *Vi, *bi, *Uo, *Vo, *bo, *Ug, *Vg, *bg;
  float* out = (float*)d_out;

  bool okA = (n_in == 13) && in_sizes[0] == 8388608 && in_sizes[1] == 524288 &&
             in_sizes[2] == 1048576 && in_sizes[3] == 1024 &&
             in_sizes[4] == 524288 && in_sizes[7] == 524288 &&
             in_sizes[10] == 524288 && in_sizes[12] == 1024;
  if (okA) {
    x = (const float*)d_in[0];
    Uf = (const float*)d_in[1];  Vf = (const float*)d_in[2];  bf = (const float*)d_in[3];
    Ui = (const float*)d_in[4];  Vi = (const float*)d_in[5];  bi = (const float*)d_in[6];
    Uo = (const float*)d_in[7];  Vo = (const float*)d_in[8];  bo = (const float*)d_in[9];
    Ug = (const float*)d_in[10]; Vg = (const float*)d_in[11]; bg = (const float*)d_in[12];
  } else {
    Uf = (const float*)d_in[0];  Ug = (const float*)d_in[1];
    Ui = (const float*)d_in[2];  Uo = (const float*)d_in[3];
    Vf = (const float*)d_in[4];  Vg = (const float*)d_in[5];
    Vi = (const float*)d_in[6];  Vo = (const float*)d_in[7];
    bf = (const float*)d_in[8];  bg = (const float*)d_in[9];
    bi = (const float*)d_in[10]; bo = (const float*)d_in[11];
    x = (const float*)d_in[12];
  }

  char* ws = (char*)d_ws;
  if (ws_size >= (size_t)WS_FULL) {
    unsigned int* flags4 = (unsigned int*)(ws + 0);
    unsigned int* vfragH = (unsigned int*)(ws + 1048576);
    unsigned int* vfragL = (unsigned int*)(ws + 9437184);
    unsigned int* ufragH = (unsigned int*)(ws + 17825792);
    unsigned int* ufragL = (unsigned int*)(ws + 22020096);
    unsigned int* xfragH = (unsigned int*)(ws + 26214400);
    unsigned int* xfragL = (unsigned int*)(ws + 42991616);
    unsigned int* hfH = (unsigned int*)(ws + 59768832);
    unsigned int* hfL = (unsigned int*)(ws + 93323264);

    (void)hipMemsetAsync(flags4, 0, 4096, stream);
    cvt_uv_kernel<<<64 * 2 * 96, 64, 0, stream>>>(Uf, Vf, Ui, Vi, Uo, Vo, Ug, Vg,
                                                  vfragH, vfragL, ufragH, ufragL);
    cvt_x_kernel<<<512, 256, 0, stream>>>(x, xfragH, xfragL);
    lstm_main<<<NWG, 512, 0, stream>>>(
        (unsigned short*)ufragH, (unsigned short*)ufragL, (unsigned short*)vfragH,
        (unsigned short*)vfragL, (unsigned short*)xfragH, (unsigned short*)xfragL,
        hfH, hfL, flags4, bf, bi, bo, bg);
    expand_out<<<8192, 256, 0, stream>>>(hfH, hfL, out);
  } else {
    float* P = (float*)ws;
    float* hbuf = (float*)(ws + 16777216);
    float* cbuf = (float*)(ws + 16908288);
    (void)hipMemsetAsync(hbuf, 0, 131072, stream);
    (void)hipMemsetAsync(cbuf, 0, 131072, stream);
    for (int t = 0; t < T_STEPS; ++t) {
      r9_step_gemm<<<dim3(32, 16), 256, 0, stream>>>(x, hbuf, Vf, Vi, Vo, Vg, Uf, Ui,
                                                     Uo, Ug, P, t);
      r9_step_cell<<<128, 256, 0, stream>>>(P, bf, bi, bo, bg, hbuf, cbuf, out, t);
    }
  }
}

// Round 17
// 3915.833 us; speedup vs baseline: 1.5065x; 1.5065x over previous
//
#include <hip/hip_runtime.h>

// CustomLSTM — Round 17: REVERT to r15 (best measured: main 3690us, total
// 3916us). r16's three bundled changes (-barrier2, per-wave flags x4, U->reg)
// regressed +54%: removing barrier-2's backpressure let waves 4-7 spin-poll
// for ~5us/step with 4x poll width, hammering the L3 flag lines the critical
// path depends on. Twice-learned lesson: polls need barrier backpressure.
//
// ws layout (121 MB):
//   0         flags   4096
//   1048576   vfragH  8388608   | 9437184  vfragL 8388608
//   17825792  ufragH  4194304   | 22020096 ufragL 4194304
//   26214400  xfragH 16777216   | 42991616 xfragL 16777216
//   59768832  hSeqH  33554432   | 93323264 hSeqL 33554432   (end 126877696)

typedef __bf16 bf16x8 __attribute__((ext_vector_type(8)));
typedef float f32x16 __attribute__((ext_vector_type(16)));

#define NWG 64
#define T_STEPS 512
#define HID 1024
#define BS 32
#define WS_FULL 126877696

__device__ __forceinline__ unsigned short f2bf(float f) {
  unsigned int u = __float_as_uint(f);
  u = (u + 0x7FFFu + ((u >> 16) & 1u)) >> 16;
  return (unsigned short)u;
}
__device__ __forceinline__ float b2f(unsigned short s) {
  return __uint_as_float(((unsigned int)s) << 16);
}
__device__ __forceinline__ float sigm(float v) {
  v = fminf(fmaxf(v, -30.f), 30.f);
  return 1.f / (1.f + __expf(-v));
}
__device__ __forceinline__ float tanh_(float v) {
  v = fminf(fmaxf(v, -15.f), 15.f);
  float e = __expf(-2.f * v);
  return (1.f - e) / (1.f + e);
}

// ---- x -> bf16 A-frags hi+lo: [t][kt 0..31][lane][4 dwords] ----
__global__ void cvt_x_kernel(const float* __restrict__ x,
                             unsigned int* __restrict__ xfH,
                             unsigned int* __restrict__ xfL) {
  const int t = blockIdx.x;
  const int tid = threadIdx.x;
  __shared__ float xs[32 * 512];
  {
    const int b = tid >> 3;
    const int k0 = (tid & 7) * 64;
    const float* src = x + ((size_t)(b * 512 + t)) * 512 + k0;
    for (int i = 0; i < 64; i += 4) {
      float4 v = *reinterpret_cast<const float4*>(src + i);
      xs[b * 512 + k0 + i + 0] = v.x;
      xs[b * 512 + k0 + i + 1] = v.y;
      xs[b * 512 + k0 + i + 2] = v.z;
      xs[b * 512 + k0 + i + 3] = v.w;
    }
  }
  __syncthreads();
  unsigned int* dH = xfH + (size_t)t * 8192;
  unsigned int* dL = xfL + (size_t)t * 8192;
  for (int i = 0; i < 32; ++i) {
    int idx = i * 256 + tid;
    int kt = idx >> 8;
    int pos = idx & 255;
    int lane = pos >> 2;
    int r = pos & 3;
    int kk = 8 * (lane >> 5) + 2 * r;
    int b2 = lane & 31;
    float f0 = xs[b2 * 512 + kt * 16 + kk];
    float f1 = xs[b2 * 512 + kt * 16 + kk + 1];
    unsigned short h0 = f2bf(f0), h1 = f2bf(f1);
    unsigned short l0 = f2bf(f0 - b2f(h0)), l1 = f2bf(f1 - b2f(h1));
    dH[idx] = (unsigned int)h0 | ((unsigned int)h1 << 16);
    dL[idx] = (unsigned int)l0 | ((unsigned int)l1 << 16);
  }
}

// ---- U,V -> B-frags hi+lo. V: kt 0..63. U: kt 64..95 ----
__global__ void cvt_uv_kernel(const float* Uf, const float* Vf,
                              const float* Ui, const float* Vi,
                              const float* Uo, const float* Vo,
                              const float* Ug, const float* Vg,
                              unsigned int* __restrict__ vfH,
                              unsigned int* __restrict__ vfL,
                              unsigned int* __restrict__ ufH,
                              unsigned int* __restrict__ ufL) {
  int blk = blockIdx.x;  // 64*2*96
  int kt = blk % 96;
  int nt = (blk / 96) & 1;
  int wg = blk / 192;
  int lane = threadIdx.x;
  int col32 = lane & 31;
  int c64 = nt * 32 + col32;
  int gate = c64 >> 4;
  int jg = wg * 16 + (c64 & 15);
  const float* V_ = (gate == 0) ? Vf : (gate == 1) ? Vi : (gate == 2) ? Vo : Vg;
  const float* U_ = (gate == 0) ? Uf : (gate == 1) ? Ui : (gate == 2) ? Uo : Ug;
  for (int r = 0; r < 4; ++r) {
    int kk = 8 * (lane >> 5) + 2 * r;
    if (kt < 64) {
      int K = kt * 16 + kk;
      float f0 = V_[(size_t)K * HID + jg];
      float f1 = V_[(size_t)(K + 1) * HID + jg];
      unsigned short h0 = f2bf(f0), h1 = f2bf(f1);
      unsigned short l0 = f2bf(f0 - b2f(h0)), l1 = f2bf(f1 - b2f(h1));
      size_t idx = ((size_t)(wg * 2 + nt) * 64 + kt) * 256 + lane * 4 + r;
      vfH[idx] = (unsigned int)h0 | ((unsigned int)h1 << 16);
      vfL[idx] = (unsigned int)l0 | ((unsigned int)l1 << 16);
    } else {
      int K = (kt - 64) * 16 + kk;
      float f0 = U_[(size_t)K * HID + jg];
      float f1 = U_[(size_t)(K + 1) * HID + jg];
      unsigned short h0 = f2bf(f0), h1 = f2bf(f1);
      unsigned short l0 = f2bf(f0 - b2f(h0)), l1 = f2bf(f1 - b2f(h1));
      size_t idx = ((size_t)(wg * 2 + nt) * 32 + (kt - 64)) * 256 + lane * 4 + r;
      ufH[idx] = (unsigned int)h0 | ((unsigned int)h1 << 16);
      ufL[idx] = (unsigned int)l0 | ((unsigned int)l1 << 16);
    }
  }
}

__device__ __forceinline__ int gidx(int nt, int w, int row, int col) {
  return ((nt * 8 + w) * 32 + row) * 32 + (col ^ row);
}

// ---- persistent recurrent kernel: 64 WGs x 512 threads (8 waves) ----
__global__ __launch_bounds__(512, 2) void lstm_main(
    const unsigned short* __restrict__ ufragH,
    const unsigned short* __restrict__ ufragL,
    const unsigned short* __restrict__ vfragH,
    const unsigned short* __restrict__ vfragL,
    const unsigned short* __restrict__ xfragH,
    const unsigned short* __restrict__ xfragL,
    unsigned int* hfH, unsigned int* hfL, unsigned int* flags,
    const float* __restrict__ bfv, const float* __restrict__ biv,
    const float* __restrict__ bov, const float* __restrict__ bgv) {
  __shared__ unsigned short ldsU[2 * 32 * 512];  // 64 KB: U hi frags
  __shared__ float gbuf[2 * 8 * 32 * 32];        // 64 KB, XOR-swizzled

  const int wg = blockIdx.x;
  const int tid = threadIdx.x;
  const int lane = tid & 63;
  const int w = tid >> 6;

  {
    const bf16x8* src = reinterpret_cast<const bf16x8*>(ufragH + (size_t)wg * 32768);
    bf16x8* dst = reinterpret_cast<bf16x8*>(ldsU);
    for (int i = 0; i < 8; ++i) dst[i * 512 + tid] = src[i * 512 + tid];
  }
  __syncthreads();
  __builtin_amdgcn_fence(__ATOMIC_ACQUIRE, "agent");  // replay-stale L2 kill

  bf16x8 uL[2][4], vH[2][8], vL[2][8];
#pragma unroll
  for (int nt = 0; nt < 2; ++nt) {
    const bf16x8* bl = reinterpret_cast<const bf16x8*>(ufragL + (size_t)wg * 32768) +
                       (size_t)nt * 32 * 64;
#pragma unroll
    for (int p = 0; p < 4; ++p) uL[nt][p] = bl[(w * 4 + p) * 64 + lane];
    const bf16x8* vh =
        reinterpret_cast<const bf16x8*>(vfragH + (size_t)((wg * 2 + nt) * 64) * 512);
    const bf16x8* vl =
        reinterpret_cast<const bf16x8*>(vfragL + (size_t)((wg * 2 + nt) * 64) * 512);
#pragma unroll
    for (int q = 0; q < 8; ++q) {
      vH[nt][q] = vh[(w * 8 + q) * 64 + lane];
      vL[nt][q] = vl[(w * 8 + q) * 64 + lane];
    }
  }

  // cell ownership (r13 mapping — conflict-free gbuf reads):
  // thread tid<256: b_ = tid&31, pair jp_ = (tid>>5)&7
  const int b_ = tid & 31;
  const int jp_ = (tid >> 5) & 7;
  const int jg0 = wg * 16 + 2 * jp_;
  const float Bf0 = bfv[jg0], Bf1 = bfv[jg0 + 1];
  const float Bi0 = biv[jg0], Bi1 = biv[jg0 + 1];
  const float Bo0 = bov[jg0], Bo1 = bov[jg0 + 1];
  const float Bg0 = bgv[jg0], Bg1 = bgv[jg0 + 1];
  float c0 = 0.f, c1 = 0.f;
  const int hw = wg * 256 + (b_ + 32 * (jp_ >> 2)) * 4 + (jp_ & 3);

#pragma unroll 1
  for (int t = 0; t < T_STEPS; ++t) {
    f32x16 acc0 = {};
    f32x16 acc1 = {};

    // ---- x@U hi+lo (no h dependency) ----
    {
      const bf16x8* axh = reinterpret_cast<const bf16x8*>(xfragH + (size_t)t * 16384);
      const bf16x8* axl = reinterpret_cast<const bf16x8*>(xfragL + (size_t)t * 16384);
      const bf16x8* lu = reinterpret_cast<const bf16x8*>(ldsU);
#pragma unroll
      for (int p = 0; p < 4; ++p) {
        int ktx = w * 4 + p;
        bf16x8 ah = axh[ktx * 64 + lane];
        bf16x8 al = axl[ktx * 64 + lane];
        bf16x8 u0 = lu[ktx * 64 + lane];
        bf16x8 u1 = lu[(32 + ktx) * 64 + lane];
        acc0 = __builtin_amdgcn_mfma_f32_32x32x16_bf16(ah, u0, acc0, 0, 0, 0);
        acc0 = __builtin_amdgcn_mfma_f32_32x32x16_bf16(ah, uL[0][p], acc0, 0, 0, 0);
        acc0 = __builtin_amdgcn_mfma_f32_32x32x16_bf16(al, u0, acc0, 0, 0, 0);
        acc1 = __builtin_amdgcn_mfma_f32_32x32x16_bf16(ah, u1, acc1, 0, 0, 0);
        acc1 = __builtin_amdgcn_mfma_f32_32x32x16_bf16(ah, uL[1][p], acc1, 0, 0, 0);
        acc1 = __builtin_amdgcn_mfma_f32_32x32x16_bf16(al, u1, acc1, 0, 0, 0);
      }
    }

    // ---- per-wave wait for THIS wave's 8 producers, then h@V ----
    if (t > 0) {
      if (lane < 8) {
        while (__hip_atomic_load(&flags[w * 8 + lane], __ATOMIC_RELAXED,
                                 __HIP_MEMORY_SCOPE_AGENT) < (unsigned int)t) {
        }
      }
      const bf16x8* ahh = reinterpret_cast<const bf16x8*>(
          reinterpret_cast<const unsigned short*>(hfH) + (size_t)(t - 1) * 32768);
      const bf16x8* ahl = reinterpret_cast<const bf16x8*>(
          reinterpret_cast<const unsigned short*>(hfL) + (size_t)(t - 1) * 32768);
      bf16x8 aH[8], aL[8];
#pragma unroll
      for (int q = 0; q < 8; ++q) {
        aH[q] = ahh[(w * 8 + q) * 64 + lane];
        aL[q] = ahl[(w * 8 + q) * 64 + lane];
      }
#pragma unroll
      for (int q = 0; q < 8; ++q) {
        acc0 = __builtin_amdgcn_mfma_f32_32x32x16_bf16(aH[q], vH[0][q], acc0, 0, 0, 0);
        acc0 = __builtin_amdgcn_mfma_f32_32x32x16_bf16(aH[q], vL[0][q], acc0, 0, 0, 0);
        acc0 = __builtin_amdgcn_mfma_f32_32x32x16_bf16(aL[q], vH[0][q], acc0, 0, 0, 0);
        acc1 = __builtin_amdgcn_mfma_f32_32x32x16_bf16(aH[q], vH[1][q], acc1, 0, 0, 0);
        acc1 = __builtin_amdgcn_mfma_f32_32x32x16_bf16(aH[q], vL[1][q], acc1, 0, 0, 0);
        acc1 = __builtin_amdgcn_mfma_f32_32x32x16_bf16(aL[q], vH[1][q], acc1, 0, 0, 0);
      }
    }

    // ---- write partial C tiles (measured C/D layout), XOR-swizzled ----
    {
      const int colw = lane & 31;
      const int rbase = 4 * (lane >> 5);
#pragma unroll
      for (int r = 0; r < 16; ++r) {
        int row = (r & 3) + 8 * (r >> 2) + rbase;
        gbuf[gidx(0, w, row, colw)] = acc0[r];
        gbuf[gidx(1, w, row, colw)] = acc1[r];
      }
    }
    __syncthreads();

    // ---- cell update (256 thr x 2 units) + register publish ----
    if (tid < 256) {
      const int jl0 = 2 * jp_, jl1 = jl0 + 1;
      float gf0 = Bf0, gf1 = Bf1, gi0 = Bi0, gi1 = Bi1;
      float go0 = Bo0, go1 = Bo1, gg0 = Bg0, gg1 = Bg1;
#pragma unroll
      for (int ww = 0; ww < 8; ++ww) {
        gf0 += gbuf[gidx(0, ww, b_, jl0)];
        gf1 += gbuf[gidx(0, ww, b_, jl1)];
        gi0 += gbuf[gidx(0, ww, b_, 16 + jl0)];
        gi1 += gbuf[gidx(0, ww, b_, 16 + jl1)];
        go0 += gbuf[gidx(1, ww, b_, jl0)];
        go1 += gbuf[gidx(1, ww, b_, jl1)];
        gg0 += gbuf[gidx(1, ww, b_, 16 + jl0)];
        gg1 += gbuf[gidx(1, ww, b_, 16 + jl1)];
      }
      c0 = sigm(gf0) * c0 + sigm(gi0) * tanh_(gg0);
      c1 = sigm(gf1) * c1 + sigm(gi1) * tanh_(gg1);
      float h0 = sigm(go0) * tanh_(c0);
      float h1 = sigm(go1) * tanh_(c1);
      unsigned short h0h = f2bf(h0), h1h = f2bf(h1);
      unsigned short h1l = f2bf(h1 - b2f(h1h));
      unsigned short h0l = f2bf(h0 - b2f(h0h));
      unsigned int hvH = (unsigned int)h0h | ((unsigned int)h1h << 16);
      unsigned int hvL = (unsigned int)h0l | ((unsigned int)h1l << 16);
      size_t base = (size_t)t * 16384 + hw;
      __hip_atomic_store(&hfH[base], hvH, __ATOMIC_RELAXED,
                         __HIP_MEMORY_SCOPE_AGENT);
      __hip_atomic_store(&hfL[base], hvL, __ATOMIC_RELAXED,
                         __HIP_MEMORY_SCOPE_AGENT);
    }
    __syncthreads();  // vmcnt(0): publishes completed at coherence point
    if (tid == 0) {
      __hip_atomic_store(&flags[wg], (unsigned int)(t + 1), __ATOMIC_RELAXED,
                         __HIP_MEMORY_SCOPE_AGENT);
    }
  }
}

// ---- epilogue: expand h planes (hi+lo bf16) -> f32 out ----
__global__ __launch_bounds__(256) void expand_out(
    const unsigned int* __restrict__ hfH, const unsigned int* __restrict__ hfL,
    float* __restrict__ out) {
  __builtin_amdgcn_fence(__ATOMIC_ACQUIRE, "agent");  // replay-stale L2 kill
  const int tid = threadIdx.x;
#pragma unroll
  for (int i = 0; i < 4; ++i) {
    size_t g = (size_t)blockIdx.x * 1024 + i * 256 + tid;
    int t = (int)(g >> 14);
    int d = (int)(g & 16383);
    int wg = d >> 8;
    int off = d & 255;
    int lane_h = off >> 2;
    int r_h = off & 3;
    int b = lane_h & 31;
    int jp = (lane_h >> 5) * 4 + r_h;
    int j0 = wg * 16 + 2 * jp;
    unsigned int uH = hfH[g];
    unsigned int uL = hfL[g];
    float f0 = b2f((unsigned short)(uH & 0xFFFF)) + b2f((unsigned short)(uL & 0xFFFF));
    float f1 = b2f((unsigned short)(uH >> 16)) + b2f((unsigned short)(uL >> 16));
    float2 v = make_float2(f0, f1);
    *reinterpret_cast<float2*>(out + 32768 + ((size_t)(b * T_STEPS + t)) * HID + j0) = v;
    if (t == T_STEPS - 1) {
      *reinterpret_cast<float2*>(out + (size_t)b * HID + j0) = v;
    }
  }
}

// ================= r9 fallback (proven) =================
__global__ __launch_bounds__(256) void r9_step_gemm(
    const float* __restrict__ x, const float* __restrict__ hbuf,
    const float* __restrict__ Vf, const float* __restrict__ Vi,
    const float* __restrict__ Vo, const float* __restrict__ Vg,
    const float* __restrict__ Uf, const float* __restrict__ Ui,
    const float* __restrict__ Uo, const float* __restrict__ Ug,
    float* __restrict__ P, int t) {
  const int kb = blockIdx.x;
  const int cb = blockIdx.y;
  const int tidx = threadIdx.x;
  const int gate = cb >> 2;
  const int j = (cb & 3) * 256 + tidx;
  const int col = cb * 256 + tidx;
  const float* V_ = (gate == 0) ? Vf : (gate == 1) ? Vi : (gate == 2) ? Vo : Vg;
  const float* U_ = (gate == 0) ? Uf : (gate == 1) ? Ui : (gate == 2) ? Uo : Ug;
  __shared__ float hs[BS][32];
  __shared__ float xs2[BS][32];
  {
    int idx = tidx * 4;
#pragma unroll
    for (int i = 0; i < 4; ++i, ++idx) {
      int b = idx >> 5, u = idx & 31;
      hs[b][u] = hbuf[b * HID + kb * 32 + u];
      if (kb < 16) xs2[b][u] = x[((size_t)b * T_STEPS + t) * 512 + kb * 32 + u];
    }
  }
  __syncthreads();
  float acc[BS];
#pragma unroll
  for (int b = 0; b < BS; ++b) acc[b] = 0.f;
  const float* vp = V_ + (size_t)(kb * 32) * HID + j;
#pragma unroll 4
  for (int k = 0; k < 32; ++k) {
    float vv = vp[(size_t)k * HID];
#pragma unroll
    for (int b = 0; b < BS; ++b) acc[b] += hs[b][k] * vv;
  }
  if (kb < 16) {
    const float* up = U_ + (size_t)(kb * 32) * HID + j;
#pragma unroll 4
    for (int k = 0; k < 32; ++k) {
      float uv = up[(size_t)k * HID];
#pragma unroll
      for (int b = 0; b < BS; ++b) acc[b] += xs2[b][k] * uv;
    }
  }
  float* pp = P + (size_t)kb * BS * 4096 + col;
#pragma unroll
  for (int b = 0; b < BS; ++b) pp[(size_t)b * 4096] = acc[b];
}

__global__ __launch_bounds__(256) void r9_step_cell(
    const float* __restrict__ P,
    const float* __restrict__ bfv, const float* __restrict__ biv,
    const float* __restrict__ bov, const float* __restrict__ bgv,
    float* __restrict__ hbuf, float* __restrict__ cbuf,
    float* __restrict__ out, int t) {
  const int idx = blockIdx.x * 256 + threadIdx.x;
  const int b = idx >> 10, j = idx & 1023;
  float gf = bfv[j], gi = biv[j], go = bov[j], gg = bgv[j];
  const float* pb = P + (size_t)b * 4096;
#pragma unroll 8
  for (int kb = 0; kb < 32; ++kb) {
    const float* pk = pb + (size_t)kb * BS * 4096;
    gf += pk[j];
    gi += pk[1024 + j];
    go += pk[2048 + j];
    gg += pk[3072 + j];
  }
  float fs = sigm(gf), is = sigm(gi), os = sigm(go), gt = tanh_(gg);
  float c = fs * cbuf[idx] + is * gt;
  cbuf[idx] = c;
  float h = os * tanh_(c);
  hbuf[idx] = h;
  out[32768 + ((size_t)b * T_STEPS + t) * HID + j] = h;
  if (t == T_STEPS - 1) out[(size_t)b * HID + j] = h;
}

extern "C" void kernel_launch(void* const* d_in, const int* in_sizes, int n_in,
                              void* d_out, int out_size, void* d_ws, size_t ws_size,
                              hipStream_t stream) {
  const float *x, *Uf, *Vf, *bf, *Ui, *Vi, *bi, *Uo, *Vo, *bo, *Ug, *Vg, *bg;
  float* out = (float*)d_out;

  bool okA = (n_in == 13) && in_sizes[0] == 8388608 && in_sizes[1] == 524288 &&
             in_sizes[2] == 1048576 && in_sizes[3] == 1024 &&
             in_sizes[4] == 524288 && in_sizes[7] == 524288 &&
             in_sizes[10] == 524288 && in_sizes[12] == 1024;
  if (okA) {
    x = (const float*)d_in[0];
    Uf = (const float*)d_in[1];  Vf = (const float*)d_in[2];  bf = (const float*)d_in[3];
    Ui = (const float*)d_in[4];  Vi = (const float*)d_in[5];  bi = (const float*)d_in[6];
    Uo = (const float*)d_in[7];  Vo = (const float*)d_in[8];  bo = (const float*)d_in[9];
    Ug = (const float*)d_in[10]; Vg = (const float*)d_in[11]; bg = (const float*)d_in[12];
  } else {
    Uf = (const float*)d_in[0];  Ug = (const float*)d_in[1];
    Ui = (const float*)d_in[2];  Uo = (const float*)d_in[3];
    Vf = (const float*)d_in[4];  Vg = (const float*)d_in[5];
    Vi = (const float*)d_in[6];  Vo = (const float*)d_in[7];
    bf = (const float*)d_in[8];  bg = (const float*)d_in[9];
    bi = (const float*)d_in[10]; bo = (const float*)d_in[11];
    x = (const float*)d_in[12];
  }

  char* ws = (char*)d_ws;
  if (ws_size >= (size_t)WS_FULL) {
    unsigned int* flags = (unsigned int*)(ws + 0);
    unsigned int* vfragH = (unsigned int*)(ws + 1048576);
    unsigned int* vfragL = (unsigned int*)(ws + 9437184);
    unsigned int* ufragH = (unsigned int*)(ws + 17825792);
    unsigned int* ufragL = (unsigned int*)(ws + 22020096);
    unsigned int* xfragH = (unsigned int*)(ws + 26214400);
    unsigned int* xfragL = (unsigned int*)(ws + 42991616);
    unsigned int* hfH = (unsigned int*)(ws + 59768832);
    unsigned int* hfL = (unsigned int*)(ws + 93323264);

    (void)hipMemsetAsync(flags, 0, 4096, stream);
    cvt_uv_kernel<<<64 * 2 * 96, 64, 0, stream>>>(Uf, Vf, Ui, Vi, Uo, Vo, Ug, Vg,
                                                  vfragH, vfragL, ufragH, ufragL);
    cvt_x_kernel<<<512, 256, 0, stream>>>(x, xfragH, xfragL);
    lstm_main<<<NWG, 512, 0, stream>>>(
        (unsigned short*)ufragH, (unsigned short*)ufragL, (unsigned short*)vfragH,
        (unsigned short*)vfragL, (unsigned short*)xfragH, (unsigned short*)xfragL,
        hfH, hfL, flags, bf, bi, bo, bg);
    expand_out<<<8192, 256, 0, stream>>>(hfH, hfL, out);
  } else {
    float* P = (float*)ws;
    float* hbuf = (float*)(ws + 16777216);
    float* cbuf = (float*)(ws + 16908288);
    (void)hipMemsetAsync(hbuf, 0, 131072, stream);
    (void)hipMemsetAsync(cbuf, 0, 131072, stream);
    for (int t = 0; t < T_STEPS; ++t) {
      r9_step_gemm<<<dim3(32, 16), 256, 0, stream>>>(x, hbuf, Vf, Vi, Vo, Vg, Uf, Ui,
                                                     Uo, Ug, P, t);
      r9_step_cell<<<128, 256, 0, stream>>>(P, bf, bi, bo, bg, hbuf, cbuf, out, t);
    }
  }
}

// Round 18
// 3874.557 us; speedup vs baseline: 1.5225x; 1.0107x over previous
//
#include <hip/hip_runtime.h>

// CustomLSTM — Round 18: r17 (=r15, best: main 3690us) + ONE change:
// 8x-replicated flag planes. The single flag region (4 lines) was polled by
// ~1024 lanes/line chip-wide while producers stored through the same lines —
// the most latency-critical store landing on the hottest line. Producer now
// stores its flag to 8 replicas (8 indep sc1 dwords, post-drain, off-path);
// consumer WG g polls only replica g>>3 -> poll fan-in per line drops 8x.
// Protocol semantics identical (monotonic counter, h-drain before flags).
//
// ws layout (121 MB):
//   0         flags   8192 (8 replicas x 64 dwords)
//   1048576   vfragH  8388608   | 9437184  vfragL 8388608
//   17825792  ufragH  4194304   | 22020096 ufragL 4194304
//   26214400  xfragH 16777216   | 42991616 xfragL 16777216
//   59768832  hSeqH  33554432   | 93323264 hSeqL 33554432   (end 126877696)

typedef __bf16 bf16x8 __attribute__((ext_vector_type(8)));
typedef float f32x16 __attribute__((ext_vector_type(16)));

#define NWG 64
#define T_STEPS 512
#define HID 1024
#define BS 32
#define WS_FULL 126877696

__device__ __forceinline__ unsigned short f2bf(float f) {
  unsigned int u = __float_as_uint(f);
  u = (u + 0x7FFFu + ((u >> 16) & 1u)) >> 16;
  return (unsigned short)u;
}
__device__ __forceinline__ float b2f(unsigned short s) {
  return __uint_as_float(((unsigned int)s) << 16);
}
__device__ __forceinline__ float sigm(float v) {
  v = fminf(fmaxf(v, -30.f), 30.f);
  return 1.f / (1.f + __expf(-v));
}
__device__ __forceinline__ float tanh_(float v) {
  v = fminf(fmaxf(v, -15.f), 15.f);
  float e = __expf(-2.f * v);
  return (1.f - e) / (1.f + e);
}

// ---- x -> bf16 A-frags hi+lo: [t][kt 0..31][lane][4 dwords] ----
__global__ void cvt_x_kernel(const float* __restrict__ x,
                             unsigned int* __restrict__ xfH,
                             unsigned int* __restrict__ xfL) {
  const int t = blockIdx.x;
  const int tid = threadIdx.x;
  __shared__ float xs[32 * 512];
  {
    const int b = tid >> 3;
    const int k0 = (tid & 7) * 64;
    const float* src = x + ((size_t)(b * 512 + t)) * 512 + k0;
    for (int i = 0; i < 64; i += 4) {
      float4 v = *reinterpret_cast<const float4*>(src + i);
      xs[b * 512 + k0 + i + 0] = v.x;
      xs[b * 512 + k0 + i + 1] = v.y;
      xs[b * 512 + k0 + i + 2] = v.z;
      xs[b * 512 + k0 + i + 3] = v.w;
    }
  }
  __syncthreads();
  unsigned int* dH = xfH + (size_t)t * 8192;
  unsigned int* dL = xfL + (size_t)t * 8192;
  for (int i = 0; i < 32; ++i) {
    int idx = i * 256 + tid;
    int kt = idx >> 8;
    int pos = idx & 255;
    int lane = pos >> 2;
    int r = pos & 3;
    int kk = 8 * (lane >> 5) + 2 * r;
    int b2 = lane & 31;
    float f0 = xs[b2 * 512 + kt * 16 + kk];
    float f1 = xs[b2 * 512 + kt * 16 + kk + 1];
    unsigned short h0 = f2bf(f0), h1 = f2bf(f1);
    unsigned short l0 = f2bf(f0 - b2f(h0)), l1 = f2bf(f1 - b2f(h1));
    dH[idx] = (unsigned int)h0 | ((unsigned int)h1 << 16);
    dL[idx] = (unsigned int)l0 | ((unsigned int)l1 << 16);
  }
}

// ---- U,V -> B-frags hi+lo. V: kt 0..63. U: kt 64..95 ----
__global__ void cvt_uv_kernel(const float* Uf, const float* Vf,
                              const float* Ui, const float* Vi,
                              const float* Uo, const float* Vo,
                              const float* Ug, const float* Vg,
                              unsigned int* __restrict__ vfH,
                              unsigned int* __restrict__ vfL,
                              unsigned int* __restrict__ ufH,
                              unsigned int* __restrict__ ufL) {
  int blk = blockIdx.x;  // 64*2*96
  int kt = blk % 96;
  int nt = (blk / 96) & 1;
  int wg = blk / 192;
  int lane = threadIdx.x;
  int col32 = lane & 31;
  int c64 = nt * 32 + col32;
  int gate = c64 >> 4;
  int jg = wg * 16 + (c64 & 15);
  const float* V_ = (gate == 0) ? Vf : (gate == 1) ? Vi : (gate == 2) ? Vo : Vg;
  const float* U_ = (gate == 0) ? Uf : (gate == 1) ? Ui : (gate == 2) ? Uo : Ug;
  for (int r = 0; r < 4; ++r) {
    int kk = 8 * (lane >> 5) + 2 * r;
    if (kt < 64) {
      int K = kt * 16 + kk;
      float f0 = V_[(size_t)K * HID + jg];
      float f1 = V_[(size_t)(K + 1) * HID + jg];
      unsigned short h0 = f2bf(f0), h1 = f2bf(f1);
      unsigned short l0 = f2bf(f0 - b2f(h0)), l1 = f2bf(f1 - b2f(h1));
      size_t idx = ((size_t)(wg * 2 + nt) * 64 + kt) * 256 + lane * 4 + r;
      vfH[idx] = (unsigned int)h0 | ((unsigned int)h1 << 16);
      vfL[idx] = (unsigned int)l0 | ((unsigned int)l1 << 16);
    } else {
      int K = (kt - 64) * 16 + kk;
      float f0 = U_[(size_t)K * HID + jg];
      float f1 = U_[(size_t)(K + 1) * HID + jg];
      unsigned short h0 = f2bf(f0), h1 = f2bf(f1);
      unsigned short l0 = f2bf(f0 - b2f(h0)), l1 = f2bf(f1 - b2f(h1));
      size_t idx = ((size_t)(wg * 2 + nt) * 32 + (kt - 64)) * 256 + lane * 4 + r;
      ufH[idx] = (unsigned int)h0 | ((unsigned int)h1 << 16);
      ufL[idx] = (unsigned int)l0 | ((unsigned int)l1 << 16);
    }
  }
}

__device__ __forceinline__ int gidx(int nt, int w, int row, int col) {
  return ((nt * 8 + w) * 32 + row) * 32 + (col ^ row);
}

// ---- persistent recurrent kernel: 64 WGs x 512 threads (8 waves) ----
__global__ __launch_bounds__(512, 2) void lstm_main(
    const unsigned short* __restrict__ ufragH,
    const unsigned short* __restrict__ ufragL,
    const unsigned short* __restrict__ vfragH,
    const unsigned short* __restrict__ vfragL,
    const unsigned short* __restrict__ xfragH,
    const unsigned short* __restrict__ xfragL,
    unsigned int* hfH, unsigned int* hfL, unsigned int* flags,
    const float* __restrict__ bfv, const float* __restrict__ biv,
    const float* __restrict__ bov, const float* __restrict__ bgv) {
  __shared__ unsigned short ldsU[2 * 32 * 512];  // 64 KB: U hi frags
  __shared__ float gbuf[2 * 8 * 32 * 32];        // 64 KB, XOR-swizzled

  const int wg = blockIdx.x;
  const int tid = threadIdx.x;
  const int lane = tid & 63;
  const int w = tid >> 6;

  {
    const bf16x8* src = reinterpret_cast<const bf16x8*>(ufragH + (size_t)wg * 32768);
    bf16x8* dst = reinterpret_cast<bf16x8*>(ldsU);
    for (int i = 0; i < 8; ++i) dst[i * 512 + tid] = src[i * 512 + tid];
  }
  __syncthreads();
  __builtin_amdgcn_fence(__ATOMIC_ACQUIRE, "agent");  // replay-stale L2 kill

  bf16x8 uL[2][4], vH[2][8], vL[2][8];
#pragma unroll
  for (int nt = 0; nt < 2; ++nt) {
    const bf16x8* bl = reinterpret_cast<const bf16x8*>(ufragL + (size_t)wg * 32768) +
                       (size_t)nt * 32 * 64;
#pragma unroll
    for (int p = 0; p < 4; ++p) uL[nt][p] = bl[(w * 4 + p) * 64 + lane];
    const bf16x8* vh =
        reinterpret_cast<const bf16x8*>(vfragH + (size_t)((wg * 2 + nt) * 64) * 512);
    const bf16x8* vl =
        reinterpret_cast<const bf16x8*>(vfragL + (size_t)((wg * 2 + nt) * 64) * 512);
#pragma unroll
    for (int q = 0; q < 8; ++q) {
      vH[nt][q] = vh[(w * 8 + q) * 64 + lane];
      vL[nt][q] = vl[(w * 8 + q) * 64 + lane];
    }
  }

  // cell ownership (r13 mapping — conflict-free gbuf reads):
  // thread tid<256: b_ = tid&31, pair jp_ = (tid>>5)&7
  const int b_ = tid & 31;
  const int jp_ = (tid >> 5) & 7;
  const int jg0 = wg * 16 + 2 * jp_;
  const float Bf0 = bfv[jg0], Bf1 = bfv[jg0 + 1];
  const float Bi0 = biv[jg0], Bi1 = biv[jg0 + 1];
  const float Bo0 = bov[jg0], Bo1 = bov[jg0 + 1];
  const float Bg0 = bgv[jg0], Bg1 = bgv[jg0 + 1];
  float c0 = 0.f, c1 = 0.f;
  const int hw = wg * 256 + (b_ + 32 * (jp_ >> 2)) * 4 + (jp_ & 3);
  const int myrep = (wg >> 3) * 64;  // this WG's flag replica base

#pragma unroll 1
  for (int t = 0; t < T_STEPS; ++t) {
    f32x16 acc0 = {};
    f32x16 acc1 = {};

    // ---- x@U hi+lo (no h dependency) ----
    {
      const bf16x8* axh = reinterpret_cast<const bf16x8*>(xfragH + (size_t)t * 16384);
      const bf16x8* axl = reinterpret_cast<const bf16x8*>(xfragL + (size_t)t * 16384);
      const bf16x8* lu = reinterpret_cast<const bf16x8*>(ldsU);
#pragma unroll
      for (int p = 0; p < 4; ++p) {
        int ktx = w * 4 + p;
        bf16x8 ah = axh[ktx * 64 + lane];
        bf16x8 al = axl[ktx * 64 + lane];
        bf16x8 u0 = lu[ktx * 64 + lane];
        bf16x8 u1 = lu[(32 + ktx) * 64 + lane];
        acc0 = __builtin_amdgcn_mfma_f32_32x32x16_bf16(ah, u0, acc0, 0, 0, 0);
        acc0 = __builtin_amdgcn_mfma_f32_32x32x16_bf16(ah, uL[0][p], acc0, 0, 0, 0);
        acc0 = __builtin_amdgcn_mfma_f32_32x32x16_bf16(al, u0, acc0, 0, 0, 0);
        acc1 = __builtin_amdgcn_mfma_f32_32x32x16_bf16(ah, u1, acc1, 0, 0, 0);
        acc1 = __builtin_amdgcn_mfma_f32_32x32x16_bf16(ah, uL[1][p], acc1, 0, 0, 0);
        acc1 = __builtin_amdgcn_mfma_f32_32x32x16_bf16(al, u1, acc1, 0, 0, 0);
      }
    }

    // ---- per-wave wait on THIS WG's flag replica, then h@V ----
    if (t > 0) {
      if (lane < 8) {
        const unsigned int* fp = &flags[myrep + w * 8 + lane];
        while (__hip_atomic_load(fp, __ATOMIC_RELAXED,
                                 __HIP_MEMORY_SCOPE_AGENT) < (unsigned int)t) {
        }
      }
      const bf16x8* ahh = reinterpret_cast<const bf16x8*>(
          reinterpret_cast<const unsigned short*>(hfH) + (size_t)(t - 1) * 32768);
      const bf16x8* ahl = reinterpret_cast<const bf16x8*>(
          reinterpret_cast<const unsigned short*>(hfL) + (size_t)(t - 1) * 32768);
      bf16x8 aH[8], aL[8];
#pragma unroll
      for (int q = 0; q < 8; ++q) {
        aH[q] = ahh[(w * 8 + q) * 64 + lane];
        aL[q] = ahl[(w * 8 + q) * 64 + lane];
      }
#pragma unroll
      for (int q = 0; q < 8; ++q) {
        acc0 = __builtin_amdgcn_mfma_f32_32x32x16_bf16(aH[q], vH[0][q], acc0, 0, 0, 0);
        acc0 = __builtin_amdgcn_mfma_f32_32x32x16_bf16(aH[q], vL[0][q], acc0, 0, 0, 0);
        acc0 = __builtin_amdgcn_mfma_f32_32x32x16_bf16(aL[q], vH[0][q], acc0, 0, 0, 0);
        acc1 = __builtin_amdgcn_mfma_f32_32x32x16_bf16(aH[q], vH[1][q], acc1, 0, 0, 0);
        acc1 = __builtin_amdgcn_mfma_f32_32x32x16_bf16(aH[q], vL[1][q], acc1, 0, 0, 0);
        acc1 = __builtin_amdgcn_mfma_f32_32x32x16_bf16(aL[q], vH[1][q], acc1, 0, 0, 0);
      }
    }

    // ---- write partial C tiles (measured C/D layout), XOR-swizzled ----
    {
      const int colw = lane & 31;
      const int rbase = 4 * (lane >> 5);
#pragma unroll
      for (int r = 0; r < 16; ++r) {
        int row = (r & 3) + 8 * (r >> 2) + rbase;
        gbuf[gidx(0, w, row, colw)] = acc0[r];
        gbuf[gidx(1, w, row, colw)] = acc1[r];
      }
    }
    __syncthreads();

    // ---- cell update (256 thr x 2 units) + register publish ----
    if (tid < 256) {
      const int jl0 = 2 * jp_, jl1 = jl0 + 1;
      float gf0 = Bf0, gf1 = Bf1, gi0 = Bi0, gi1 = Bi1;
      float go0 = Bo0, go1 = Bo1, gg0 = Bg0, gg1 = Bg1;
#pragma unroll
      for (int ww = 0; ww < 8; ++ww) {
        gf0 += gbuf[gidx(0, ww, b_, jl0)];
        gf1 += gbuf[gidx(0, ww, b_, jl1)];
        gi0 += gbuf[gidx(0, ww, b_, 16 + jl0)];
        gi1 += gbuf[gidx(0, ww, b_, 16 + jl1)];
        go0 += gbuf[gidx(1, ww, b_, jl0)];
        go1 += gbuf[gidx(1, ww, b_, jl1)];
        gg0 += gbuf[gidx(1, ww, b_, 16 + jl0)];
        gg1 += gbuf[gidx(1, ww, b_, 16 + jl1)];
      }
      c0 = sigm(gf0) * c0 + sigm(gi0) * tanh_(gg0);
      c1 = sigm(gf1) * c1 + sigm(gi1) * tanh_(gg1);
      float h0 = sigm(go0) * tanh_(c0);
      float h1 = sigm(go1) * tanh_(c1);
      unsigned short h0h = f2bf(h0), h1h = f2bf(h1);
      unsigned short h1l = f2bf(h1 - b2f(h1h));
      unsigned short h0l = f2bf(h0 - b2f(h0h));
      unsigned int hvH = (unsigned int)h0h | ((unsigned int)h1h << 16);
      unsigned int hvL = (unsigned int)h0l | ((unsigned int)h1l << 16);
      size_t base = (size_t)t * 16384 + hw;
      __hip_atomic_store(&hfH[base], hvH, __ATOMIC_RELAXED,
                         __HIP_MEMORY_SCOPE_AGENT);
      __hip_atomic_store(&hfL[base], hvL, __ATOMIC_RELAXED,
                         __HIP_MEMORY_SCOPE_AGENT);
    }
    __syncthreads();  // vmcnt(0): publishes completed at coherence point
    if (tid == 0) {
      // store flag to all 8 replicas (independent lines, issue-pipelined)
#pragma unroll
      for (int r = 0; r < 8; ++r) {
        __hip_atomic_store(&flags[r * 64 + wg], (unsigned int)(t + 1),
                           __ATOMIC_RELAXED, __HIP_MEMORY_SCOPE_AGENT);
      }
    }
  }
}

// ---- epilogue: expand h planes (hi+lo bf16) -> f32 out ----
__global__ __launch_bounds__(256) void expand_out(
    const unsigned int* __restrict__ hfH, const unsigned int* __restrict__ hfL,
    float* __restrict__ out) {
  __builtin_amdgcn_fence(__ATOMIC_ACQUIRE, "agent");  // replay-stale L2 kill
  const int tid = threadIdx.x;
#pragma unroll
  for (int i = 0; i < 4; ++i) {
    size_t g = (size_t)blockIdx.x * 1024 + i * 256 + tid;
    int t = (int)(g >> 14);
    int d = (int)(g & 16383);
    int wg = d >> 8;
    int off = d & 255;
    int lane_h = off >> 2;
    int r_h = off & 3;
    int b = lane_h & 31;
    int jp = (lane_h >> 5) * 4 + r_h;
    int j0 = wg * 16 + 2 * jp;
    unsigned int uH = hfH[g];
    unsigned int uL = hfL[g];
    float f0 = b2f((unsigned short)(uH & 0xFFFF)) + b2f((unsigned short)(uL & 0xFFFF));
    float f1 = b2f((unsigned short)(uH >> 16)) + b2f((unsigned short)(uL >> 16));
    float2 v = make_float2(f0, f1);
    *reinterpret_cast<float2*>(out + 32768 + ((size_t)(b * T_STEPS + t)) * HID + j0) = v;
    if (t == T_STEPS - 1) {
      *reinterpret_cast<float2*>(out + (size_t)b * HID + j0) = v;
    }
  }
}

// ================= r9 fallback (proven) =================
__global__ __launch_bounds__(256) void r9_step_gemm(
    const float* __restrict__ x, const float* __restrict__ hbuf,
    const float* __restrict__ Vf, const float* __restrict__ Vi,
    const float* __restrict__ Vo, const float* __restrict__ Vg,
    const float* __restrict__ Uf, const float* __restrict__ Ui,
    const float* __restrict__ Uo, const float* __restrict__ Ug,
    float* __restrict__ P, int t) {
  const int kb = blockIdx.x;
  const int cb = blockIdx.y;
  const int tidx = threadIdx.x;
  const int gate = cb >> 2;
  const int j = (cb & 3) * 256 + tidx;
  const int col = cb * 256 + tidx;
  const float* V_ = (gate == 0) ? Vf : (gate == 1) ? Vi : (gate == 2) ? Vo : Vg;
  const float* U_ = (gate == 0) ? Uf : (gate == 1) ? Ui : (gate == 2) ? Uo : Ug;
  __shared__ float hs[BS][32];
  __shared__ float xs2[BS][32];
  {
    int idx = tidx * 4;
#pragma unroll
    for (int i = 0; i < 4; ++i, ++idx) {
      int b = idx >> 5, u = idx & 31;
      hs[b][u] = hbuf[b * HID + kb * 32 + u];
      if (kb < 16) xs2[b][u] = x[((size_t)b * T_STEPS + t) * 512 + kb * 32 + u];
    }
  }
  __syncthreads();
  float acc[BS];
#pragma unroll
  for (int b = 0; b < BS; ++b) acc[b] = 0.f;
  const float* vp = V_ + (size_t)(kb * 32) * HID + j;
#pragma unroll 4
  for (int k = 0; k < 32; ++k) {
    float vv = vp[(size_t)k * HID];
#pragma unroll
    for (int b = 0; b < BS; ++b) acc[b] += hs[b][k] * vv;
  }
  if (kb < 16) {
    const float* up = U_ + (size_t)(kb * 32) * HID + j;
#pragma unroll 4
    for (int k = 0; k < 32; ++k) {
      float uv = up[(size_t)k * HID];
#pragma unroll
      for (int b = 0; b < BS; ++b) acc[b] += xs2[b][k] * uv;
    }
  }
  float* pp = P + (size_t)kb * BS * 4096 + col;
#pragma unroll
  for (int b = 0; b < BS; ++b) pp[(size_t)b * 4096] = acc[b];
}

__global__ __launch_bounds__(256) void r9_step_cell(
    const float* __restrict__ P,
    const float* __restrict__ bfv, const float* __restrict__ biv,
    const float* __restrict__ bov, const float* __restrict__ bgv,
    float* __restrict__ hbuf, float* __restrict__ cbuf,
    float* __restrict__ out, int t) {
  const int idx = blockIdx.x * 256 + threadIdx.x;
  const int b = idx >> 10, j = idx & 1023;
  float gf = bfv[j], gi = biv[j], go = bov[j], gg = bgv[j];
  const float* pb = P + (size_t)b * 4096;
#pragma unroll 8
  for (int kb = 0; kb < 32; ++kb) {
    const float* pk = pb + (size_t)kb * BS * 4096;
    gf += pk[j];
    gi += pk[1024 + j];
    go += pk[2048 + j];
    gg += pk[3072 + j];
  }
  float fs = sigm(gf), is = sigm(gi), os = sigm(go), gt = tanh_(gg);
  float c = fs * cbuf[idx] + is * gt;
  cbuf[idx] = c;
  float h = os * tanh_(c);
  hbuf[idx] = h;
  out[32768 + ((size_t)b * T_STEPS + t) * HID + j] = h;
  if (t == T_STEPS - 1) out[(size_t)b * HID + j] = h;
}

extern "C" void kernel_launch(void* const* d_in, const int* in_sizes, int n_in,
                              void* d_out, int out_size, void* d_ws, size_t ws_size,
                              hipStream_t stream) {
  const float *x, *Uf, *Vf, *bf, *Ui, *Vi, *bi, *Uo, *Vo, *bo, *Ug, *Vg, *bg;
  float* out = (float*)d_out;

  bool okA = (n_in == 13) && in_sizes[0] == 8388608 && in_sizes[1] == 524288 &&
             in_sizes[2] == 1048576 && in_sizes[3] == 1024 &&
             in_sizes[4] == 524288 && in_sizes[7] == 524288 &&
             in_sizes[10] == 524288 && in_sizes[12] == 1024;
  if (okA) {
    x = (const float*)d_in[0];
    Uf = (const float*)d_in[1];  Vf = (const float*)d_in[2];  bf = (const float*)d_in[3];
    Ui = (const float*)d_in[4];  Vi = (const float*)d_in[5];  bi = (const float*)d_in[6];
    Uo = (const float*)d_in[7];  Vo = (const float*)d_in[8];  bo = (const float*)d_in[9];
    Ug = (const float*)d_in[10]; Vg = (const float*)d_in[11]; bg = (const float*)d_in[12];
  } else {
    Uf = (const float*)d_in[0];  Ug = (const float*)d_in[1];
    Ui = (const float*)d_in[2];  Uo = (const float*)d_in[3];
    Vf = (const float*)d_in[4];  Vg = (const float*)d_in[5];
    Vi = (const float*)d_in[6];  Vo = (const float*)d_in[7];
    bf = (const float*)d_in[8];  bg = (const float*)d_in[9];
    bi = (const float*)d_in[10]; bo = (const float*)d_in[11];
    x = (const float*)d_in[12];
  }

  char* ws = (char*)d_ws;
  if (ws_size >= (size_t)WS_FULL) {
    unsigned int* flags = (unsigned int*)(ws + 0);
    unsigned int* vfragH = (unsigned int*)(ws + 1048576);
    unsigned int* vfragL = (unsigned int*)(ws + 9437184);
    unsigned int* ufragH = (unsigned int*)(ws + 17825792);
    unsigned int* ufragL = (unsigned int*)(ws + 22020096);
    unsigned int* xfragH = (unsigned int*)(ws + 26214400);
    unsigned int* xfragL = (unsigned int*)(ws + 42991616);
    unsigned int* hfH = (unsigned int*)(ws + 59768832);
    unsigned int* hfL = (unsigned int*)(ws + 93323264);

    (void)hipMemsetAsync(flags, 0, 8192, stream);
    cvt_uv_kernel<<<64 * 2 * 96, 64, 0, stream>>>(Uf, Vf, Ui, Vi, Uo, Vo, Ug, Vg,
                                                  vfragH, vfragL, ufragH, ufragL);
    cvt_x_kernel<<<512, 256, 0, stream>>>(x, xfragH, xfragL);
    lstm_main<<<NWG, 512, 0, stream>>>(
        (unsigned short*)ufragH, (unsigned short*)ufragL, (unsigned short*)vfragH,
        (unsigned short*)vfragL, (unsigned short*)xfragH, (unsigned short*)xfragL,
        hfH, hfL, flags, bf, bi, bo, bg);
    expand_out<<<8192, 256, 0, stream>>>(hfH, hfL, out);
  } else {
    float* P = (float*)ws;
    float* hbuf = (float*)(ws + 16777216);
    float* cbuf = (float*)(ws + 16908288);
    (void)hipMemsetAsync(hbuf, 0, 131072, stream);
    (void)hipMemsetAsync(cbuf, 0, 131072, stream);
    for (int t = 0; t < T_STEPS; ++t) {
      r9_step_gemm<<<dim3(32, 16), 256, 0, stream>>>(x, hbuf, Vf, Vi, Vo, Vg, Uf, Ui,
                                                     Uo, Ug, P, t);
      r9_step_cell<<<128, 256, 0, stream>>>(P, bf, bi, bo, bg, hbuf, cbuf, out, t);
    }
  }
}